// Round 1
// baseline (249.734 us; speedup 1.0000x reference)
//
#include <hip/hip_runtime.h>
#include <hip/hip_bf16.h>
#include <cstdint>
#include <cstddef>

typedef __hip_bfloat16 bf16;
typedef __attribute__((ext_vector_type(8))) short short8;   // 8 bf16 = 4 VGPRs
typedef __attribute__((ext_vector_type(4))) short s4v;      // 4 bf16 = 2 VGPRs
typedef __attribute__((ext_vector_type(4))) float floatx4;

#define B_ 2
#define S_ 2048
#define D_ 1024
#define H_ 16
#define DK_ 64
#define M_ 4096
#define HEADELEMS 131072   // S_*DK_ per (b,h)
#define TILEELEMS 4096     // 64*64 per 64-token tile
#define QSCALE 0.1803368801111204f   // 0.125 * log2(e), folded into Q projection

struct __align__(8) bf16x4 { bf16 x, y, z, w; };

__device__ __forceinline__ floatx4 mfma16(short8 a, short8 b, floatx4 c) {
  return __builtin_amdgcn_mfma_f32_16x16x32_bf16(a, b, c, 0, 0, 0);
}
__device__ __forceinline__ void gl_lds16(const bf16* g, bf16* l) {
  __builtin_amdgcn_global_load_lds((const __attribute__((address_space(1))) void*)g,
                                   (__attribute__((address_space(3))) void*)l, 16, 0, 0);
}
__device__ __forceinline__ float bs2f(short s) {
  bf16 b = *reinterpret_cast<bf16*>(&s);
  return __bfloat162float(b);
}
__device__ __forceinline__ s4v pack4(float p0, float p1, float p2, float p3) {
  union { __hip_bfloat162 h; short2 s; } ua, ub;
  ua.h = __float22bfloat162_rn(make_float2(p0, p1));
  ub.h = __float22bfloat162_rn(make_float2(p2, p3));
  s4v r = {ua.s.x, ua.s.y, ub.s.x, ub.s.y};
  return r;
}
__device__ __forceinline__ float fast_exp2(float x) {
#if __has_builtin(__builtin_amdgcn_exp2f)
  return __builtin_amdgcn_exp2f(x);    // raw v_exp_f32 (no OCML range fixup)
#else
  float r; asm("v_exp_f32 %0, %1" : "=v"(r) : "v"(x)); return r;
#endif
}

// ---------------- fused prep: fp32->bf16 converts + weight transposes + mask detect ----------------
// blocks [0,12288): converts (z = blk/4096); [12288,13312): transposes (z = (blk-12288)/256);
// block 13312: padding-mask dtype detector.
__global__ void prep_kernel(const float* __restrict__ q_in, const float* __restrict__ k_in,
                            const float* __restrict__ v_in,
                            const float* __restrict__ Wq, const float* __restrict__ Wk,
                            const float* __restrict__ Wv, const float* __restrict__ Wo,
                            bf16* __restrict__ xq, bf16* __restrict__ xk, bf16* __restrict__ xv,
                            bf16* __restrict__ wqt, bf16* __restrict__ wkt,
                            bf16* __restrict__ wvt, bf16* __restrict__ wot,
                            const unsigned int* __restrict__ pmask, int* __restrict__ flag) {
  __shared__ bf16 tile[64][66];
  __shared__ int sbyte;
  const int blk = blockIdx.x;
  const int tid = threadIdx.x;
  if (blk < 12288) {
    const int z = blk >> 12;
    const int i = ((blk & 4095) << 8) | tid;
    const float* src = (z == 0) ? q_in : (z == 1) ? k_in : v_in;
    bf16* dst = (z == 0) ? xq : (z == 1) ? xk : xv;
    float4 v = ((const float4*)src)[i];
    bf16x4 o = { __float2bfloat16(v.x), __float2bfloat16(v.y),
                 __float2bfloat16(v.z), __float2bfloat16(v.w) };
    ((bf16x4*)dst)[i] = o;
  } else if (blk < 13312) {
    const int t = blk - 12288;
    const int z = t >> 8;
    const int rc = t & 255;
    const int r0 = (rc >> 4) * 64, c0 = (rc & 15) * 64;
    const float* src = (z == 0) ? Wq : (z == 1) ? Wk : (z == 2) ? Wv : Wo;
    bf16* dst = (z == 0) ? wqt : (z == 1) ? wkt : (z == 2) ? wvt : wot;
    const int lr = tid >> 4;
    const int lc4 = (tid & 15) * 4;
#pragma unroll
    for (int i = 0; i < 4; ++i) {
      const int r = lr + i * 16;
      float4 v = *(const float4*)(src + (size_t)(r0 + r) * D_ + c0 + lc4);
      tile[r][lc4 + 0] = __float2bfloat16(v.x);
      tile[r][lc4 + 1] = __float2bfloat16(v.y);
      tile[r][lc4 + 2] = __float2bfloat16(v.z);
      tile[r][lc4 + 3] = __float2bfloat16(v.w);
    }
    __syncthreads();
    const int orr = tid & 63;
    const int oc0 = tid >> 6;
#pragma unroll
    for (int j = 0; j < 16; ++j) {
      const int oc = oc0 + j * 4;
      dst[(size_t)(c0 + oc) * D_ + r0 + orr] = tile[orr][oc];
    }
  } else {
    if (tid == 0) sbyte = 0;
    __syncthreads();
    for (int i = tid; i < (B_ * S_) / 4; i += 256) {
      const unsigned int v = pmask[i];
      if (((v & 0xFEFEFEFEu) == 0u) && ((v & 0xFFFFFF00u) != 0u)) sbyte = 1;
    }
    __syncthreads();
    if (tid == 0) *flag = sbyte;
  }
}

// ---------------- bf16 GEMM, C = A[M,K] * W[N,K]^T + bias ----------------
// mode 0: bf16 out, Q/K fragment-swizzled per-head tiles (LDS-bounced coalesced stores)
// mode 1: bf16 out, V^T fragment-swizzled per-head tiles (LDS-bounced coalesced stores)
// mode 2: fp32 out, plain [M][N]
template<int MT>
__global__ __launch_bounds__(256, 2) void gemm_k(
    const bf16* __restrict__ A0, const bf16* __restrict__ A1, const bf16* __restrict__ A2,
    const bf16* __restrict__ W0, const bf16* __restrict__ W1, const bf16* __restrict__ W2,
    const float* __restrict__ b0, const float* __restrict__ b1, const float* __restrict__ b2,
    void* __restrict__ O0, void* __restrict__ O1, void* __restrict__ O2,
    const int mode01, const int Kd, const float sc)
{
  __shared__ __align__(16) bf16 sh[(MT + 128) * 32];   // As | Bs, contiguous
  bf16* As = sh;
  bf16* Bs = sh + MT * 32;
  const int z = blockIdx.z;
  const bf16* A = (z == 0) ? A0 : (z == 1) ? A1 : A2;
  const bf16* W = (z == 0) ? W0 : (z == 1) ? W1 : W2;
  const float* bias = (z == 0) ? b0 : (z == 1) ? b1 : b2;
  void* Cout = (z == 0) ? O0 : (z == 1) ? O1 : O2;
  const int mode = (z == 2) ? 1 : mode01;
  const float scz = (z == 0) ? sc : 1.f;

  constexpr int MI = MT / 32;
  const int tid = threadIdx.x;
  const int wave = tid >> 6, lane = tid & 63;
  const int quad = lane >> 4, lc = lane & 15;
  const int wm = (wave >> 1) * (MT / 2), wn = (wave & 1) * 64;
  const int m0 = blockIdx.y * MT, n0 = blockIdx.x * 128;

  const floatx4 zero4 = {0.f, 0.f, 0.f, 0.f};
  floatx4 acc[MI][4];
#pragma unroll
  for (int mi = 0; mi < MI; ++mi)
#pragma unroll
    for (int ni = 0; ni < 4; ++ni) acc[mi][ni] = zero4;

  const int ldr = lane >> 2;
  const int ldc = (lane & 3) * 8;
  const bf16* Ag = A + (size_t)(m0 + wave * (MT / 4) + ldr) * Kd + ldc;
  const bf16* Bg = W + (size_t)(n0 + wave * 32 + ldr) * Kd + ldc;
  bf16* As0 = As + wave * (MT / 4) * 32;
  bf16* Bs0 = Bs + wave * 32 * 32;

  for (int k0 = 0; k0 < Kd; k0 += 32) {
    gl_lds16(Ag + k0, As0);
    if (MT == 128) gl_lds16(Ag + k0 + (size_t)16 * Kd, As0 + 16 * 32);
    gl_lds16(Bg + k0, Bs0);
    gl_lds16(Bg + k0 + (size_t)16 * Kd, Bs0 + 16 * 32);
    __syncthreads();

    short8 af[MI], bfr[4];
#pragma unroll
    for (int i = 0; i < MI; ++i)
      af[i] = *(const short8*)(As + (wm + i * 16 + lc) * 32 + quad * 8);
#pragma unroll
    for (int i = 0; i < 4; ++i)
      bfr[i] = *(const short8*)(Bs + (wn + i * 16 + lc) * 32 + quad * 8);
#pragma unroll
    for (int mi = 0; mi < MI; ++mi)
#pragma unroll
      for (int ni = 0; ni < 4; ++ni)
        acc[mi][ni] = mfma16(af[mi], bfr[ni], acc[mi][ni]);
    __syncthreads();
  }

  if (mode == 2) {
    float* out = (float*)Cout;
#pragma unroll
    for (int mi = 0; mi < MI; ++mi)
#pragma unroll
      for (int ni = 0; ni < 4; ++ni) {
        const int col = n0 + wn + ni * 16 + lc;
        const float bv = bias[col];
        const int rbase = m0 + wm + mi * 16 + quad * 4;
#pragma unroll
        for (int r = 0; r < 4; ++r)
          out[(size_t)(rbase + r) * D_ + col] = acc[mi][ni][r] + bv;
      }
  } else {
    // LDS-bounce: this wave's 64x64 quadrant == one (T, head) swizzled tile.
    bf16* pool = sh + wave * 2048;
    float bvs[4];
#pragma unroll
    for (int ni = 0; ni < 4; ++ni) bvs[ni] = bias[n0 + wn + ni * 16 + lc];
    const int hcol = (n0 + wn) >> 6;
    const int mglob = m0 + wm;
    bf16* outb = (bf16*)Cout + (size_t)((mglob >> 11) * H_ + hcol) * HEADELEMS
               + (size_t)((mglob & (S_ - 1)) >> 6) * TILEELEMS;
#pragma unroll
    for (int half = 0; half < MI / 2; ++half) {
#pragma unroll
      for (int mi2 = 0; mi2 < 2; ++mi2) {
        const int mi = half * 2 + mi2;
#pragma unroll
        for (int ni = 0; ni < 4; ++ni) {
          const int dkl = ni * 16 + lc;
#pragma unroll
          for (int r = 0; r < 4; ++r) {
            const float v = (acc[mi][ni][r] + bvs[ni]) * scz;
            int idx;
            if (mode == 0) {
              const int c = (mi2 * 2 + (dkl >> 5)) * 64 + ((dkl >> 3) & 3) * 16 + quad * 4 + r;
              idx = c * 8 + (dkl & 7);
            } else {
              const int c = (mi2 * 4 + (dkl >> 4)) * 64 + quad * 16 + (dkl & 15);
              idx = c * 4 + r;
            }
            pool[idx] = __float2bfloat16(v);
          }
        }
      }
#pragma unroll
      for (int t = 0; t < 4; ++t) {
        const short8 vv = *(const short8*)(pool + t * 512 + lane * 8);
        *(short8*)(outb + half * 2048 + t * 512 + lane * 8) = vv;
      }
    }
  }
}

// ---------------- V suffix sums ----------------
__global__ void suf_kernel(const bf16* __restrict__ vp, float* __restrict__ suf) {
  __shared__ float ts[32 * 64];
  const int bhid = blockIdx.x;
  const bf16* vb = vp + (size_t)bhid * HEADELEMS;
  const int tid = threadIdx.x;
  const int dk = tid & 63, g = tid >> 6;
  const int dkt = dk >> 4, lck = dk & 15;
  for (int T = g * 8; T < g * 8 + 8; ++T) {
    float sum = 0.f;
#pragma unroll
    for (int w = 0; w < 4; ++w)
#pragma unroll
      for (int qd = 0; qd < 4; ++qd) {
        const s4v x = *(const s4v*)(vb + (size_t)T * TILEELEMS
                                    + (size_t)(((w * 4 + dkt) * 64 + qd * 16 + lck)) * 4);
        sum += bs2f(x[0]) + bs2f(x[1]) + bs2f(x[2]) + bs2f(x[3]);
      }
    ts[T * 64 + dk] = sum;
  }
  __syncthreads();
  if (g == 0) {
    float run = 0.f;
    float* out = suf + (size_t)bhid * (33 * 64);
    out[32 * 64 + dk] = 0.f;
    for (int T = 31; T >= 0; --T) { run += ts[T * 64 + dk]; out[T * 64 + dk] = run; }
  }
}

// ---------------- fused attention ----------------
__device__ __forceinline__ void load_pad(const void* pad, int bytemode, int idx, bool pm[4]) {
  if (bytemode) {
    const uchar4 u = *(const uchar4*)((const unsigned char*)pad + idx);
    pm[0] = u.x != 0; pm[1] = u.y != 0; pm[2] = u.z != 0; pm[3] = u.w != 0;
  } else {
    const int4 u = *(const int4*)((const int*)pad + idx);
    pm[0] = u.x != 0; pm[1] = u.y != 0; pm[2] = u.z != 0; pm[3] = u.w != 0;
  }
}

// register-resident fragments for one p-step (2 key tiles): K (4x short8),
// V^T (8x s4v), pad bools. Prefetched one step ahead of compute.
struct KVF {
  short8 ak00, ak01, ak10, ak11;
  s4v va0[4], va1[4];
  bool pm0[4], pm1[4];
};

__device__ __forceinline__ void load_kv(const bf16* kwp, const bf16* vwp,
                                        const void* pad, const int bytemode,
                                        const int pidx, const int p, KVF& f) {
  const size_t o0 = (size_t)(2 * p) * TILEELEMS, o1 = o0 + TILEELEMS;
  f.ak00 = *(const short8*)(kwp + o0);
  f.ak01 = *(const short8*)(kwp + o0 + 512);
  f.ak10 = *(const short8*)(kwp + o1);
  f.ak11 = *(const short8*)(kwp + o1 + 512);
#pragma unroll
  for (int dkt = 0; dkt < 4; ++dkt) {
    f.va0[dkt] = *(const s4v*)(vwp + o0 + dkt * 256);
    f.va1[dkt] = *(const s4v*)(vwp + o1 + dkt * 256);
  }
  load_pad(pad, bytemode, pidx + 2 * p * 64, f.pm0);
  load_pad(pad, bytemode, pidx + (2 * p + 1) * 64, f.pm1);
}

// S^T = K*Q^T for one 64-key tile (wave owns 16-key strip); mask+exp -> pf (P^T, B-frag-ready)
// Q pre-scaled by 0.125*log2(e) at projection time. DIAGP=false compiles the
// branch-free clean-loop body (diag logic folded away).
template<bool DIAGP>
__device__ __forceinline__ void qk_tile(const short8 ak0, const short8 ak1,
                                        const short8 (&qf)[4][2],
                                        const bool pm[4], float (&lacc)[4], s4v (&pf)[4],
                                        const int w, const int quad, const int lc,
                                        const bool diag) {
  const floatx4 z4 = {0.f, 0.f, 0.f, 0.f};
  const short ONE = (short)0x3F80;
#pragma unroll
  for (int qt = 0; qt < 4; ++qt) {
    if (DIAGP && diag && w > qt) { // strictly-upper 16x16 subtile: all masked -> p = 1
      s4v o1 = {ONE, ONE, ONE, ONE};
      pf[qt] = o1;
      lacc[qt] += 4.f;
      continue;
    }
    floatx4 s = mfma16(ak0, qf[qt][0], z4);
    s = mfma16(ak1, qf[qt][1], s);
    float pv[4];
#pragma unroll
    for (int r = 0; r < 4; ++r) {
      bool m = pm[r];
      if (DIAGP && diag && w == qt) m = m || (quad * 4 + r > lc);
      pv[r] = fast_exp2(m ? 0.f : s[r]);
      lacc[qt] += pv[r];
    }
    pf[qt] = pack4(pv[0], pv[1], pv[2], pv[3]);
  }
}

__device__ __forceinline__ void pv_step(const KVF& f, const s4v (&pf0)[4], const s4v (&pf1)[4],
                                        floatx4 (&oacc)[4][4]) {
  short8 pB[4];
#pragma unroll
  for (int qt = 0; qt < 4; ++qt)
    pB[qt] = __builtin_shufflevector(pf0[qt], pf1[qt], 0, 1, 2, 3, 4, 5, 6, 7);
#pragma unroll
  for (int dkt = 0; dkt < 4; ++dkt) {
    const short8 av = __builtin_shufflevector(f.va0[dkt], f.va1[dkt], 0, 1, 2, 3, 4, 5, 6, 7);
#pragma unroll
    for (int qt = 0; qt < 4; ++qt)
      oacc[dkt][qt] = mfma16(av, pB[qt], oacc[dkt][qt]);
  }
}

// Barrier-free main loop, register-prefetched one p-step ahead. Each block owns the
// uniform q-tile PAIR (31-j, j): every pair costs exactly 17 p-steps, so all 512
// blocks (2/CU) finish together — no triangular tail. K/V fragments load DIRECTLY
// from the swizzled global layout (L2-local: bh & 7 == XCD). The diagonal p-step is
// peeled so the main loop is branch-free and software-pipelines cleanly.
__global__ __launch_bounds__(256, 1) void attn_kernel(
    const bf16* __restrict__ qp, const bf16* __restrict__ kp,
    const bf16* __restrict__ vp, const float* __restrict__ suf,
    const void* __restrict__ pad, const int* __restrict__ flag,
    bf16* __restrict__ oa)
{
  __shared__ __align__(16) bf16 smem[13312];   // epilogue only: fbuf 17408B | obuf 9216B
  __shared__ float lbuf[256];

  const int lin = blockIdx.x;          // 512 blocks
  const int xcd = lin & 7;
  const int t = lin >> 3;              // 0..63
  const int grp = t >> 4;              // 0..3
  const int jq = t & 15;               // q-pair (31-jq, jq): mynp sums to 17 for all jq
  const int bh = xcd + 8 * grp;
  const int b = bh >> 4, h = bh & 15;

  const int tid = threadIdx.x;
  const int w = tid >> 6, lane = tid & 63, quad = lane >> 4, lc = lane & 15;
  const int bytemode = *flag;
  const int pidx = b * S_ + w * 16 + quad * 4;

  // per-wave direct-load base pointers into swizzled K / V^T (shared by both q-tiles)
  const bf16* kwp = kp + (size_t)bh * HEADELEMS + (size_t)(w * 128 + lane) * 8;
  const bf16* vwp = vp + (size_t)bh * HEADELEMS + (size_t)(w * 4 * 64 + lane) * 4;

#pragma unroll 1
  for (int qsel = 0; qsel < 2; ++qsel) {
    const int myqt = qsel ? jq : 31 - jq;
    const int mynt = myqt + 1;
    const int pfull = (mynt - 1) >> 1;     // clean (non-diag) p-steps

    // Q fragments (B-operand for S^T = K*Q^T), fragment-linear in global
    const bf16* qb = qp + (size_t)bh * HEADELEMS + (size_t)myqt * TILEELEMS;
    short8 qf[4][2];
#pragma unroll
    for (int qt = 0; qt < 4; ++qt)
#pragma unroll
      for (int hh = 0; hh < 2; ++hh)
        qf[qt][hh] = *(const short8*)(qb + (size_t)((qt * 2 + hh) * 64 + lane) * 8);

    const floatx4 zero4 = {0.f, 0.f, 0.f, 0.f};
    floatx4 oacc[4][4];                            // [dkt][qt]
#pragma unroll
    for (int i = 0; i < 4; ++i)
#pragma unroll
      for (int jj = 0; jj < 4; ++jj) oacc[i][jj] = zero4;
    float lacc[4] = {0.f, 0.f, 0.f, 0.f};

    KVF f;
    load_kv(kwp, vwp, pad, bytemode, pidx, 0, f);
#pragma unroll 1
    for (int p = 0; p < pfull; ++p) {
      KVF fn;
      load_kv(kwp, vwp, pad, bytemode, pidx, p + 1, fn);   // prefetch next step
      s4v pf0[4], pf1[4];
      qk_tile<false>(f.ak00, f.ak01, qf, f.pm0, lacc, pf0, w, quad, lc, false);
      qk_tile<false>(f.ak10, f.ak11, qf, f.pm1, lacc, pf1, w, quad, lc, false);
      pv_step(f, pf0, pf1, oacc);
      f = fn;
    }
    {  // peeled tail step: contains the diagonal tile (and phantom T1 when mynt odd)
      const int T0 = 2 * pfull, T1 = T0 + 1;
      s4v pf0[4], pf1[4];
      qk_tile<true>(f.ak00, f.ak01, qf, f.pm0, lacc, pf0, w, quad, lc, T0 == mynt - 1);
      if (T1 < mynt) {
        qk_tile<true>(f.ak10, f.ak11, qf, f.pm1, lacc, pf1, w, quad, lc, T1 == mynt - 1);
      } else {
        const s4v zz = {0, 0, 0, 0};
#pragma unroll
        for (int qt = 0; qt < 4; ++qt) pf1[qt] = zz;   // phantom: covered by suffix sums
      }
      pv_step(f, pf0, pf1, oacc);
    }

    // ---- epilogue: cross-strip reduction -> LDS out-tile -> full-128B-line stores ----
#pragma unroll
    for (int qt = 0; qt < 4; ++qt) {
      float v = lacc[qt];
      v += __shfl_xor(v, 16);
      v += __shfl_xor(v, 32);
      if (quad == 0) lbuf[w * 64 + qt * 16 + lc] = v;
    }
    __syncthreads();
    float* fbuf = (float*)smem;                    // 16 tiles x (16 rows x stride 17) floats
    bf16* obuf = smem + 8704;                      // 64 rows x stride 72 = 9216 B
    float ls = lbuf[0 * 64 + w * 16 + lc] + lbuf[1 * 64 + w * 16 + lc]
             + lbuf[2 * 64 + w * 16 + lc] + lbuf[3 * 64 + w * 16 + lc];
    ls += (float)(S_ - mynt * 64);                 // keys past diagonal tile: weight 1 each
    const float linv = 1.f / ls;
    const float* sufp = suf + (size_t)bh * (33 * 64) + mynt * 64;

#pragma unroll
    for (int dktG = 0; dktG < 4; ++dktG) {
#pragma unroll
      for (int qt = 0; qt < 4; ++qt) {
        const floatx4 a = oacc[dktG][qt];
        float* dst = fbuf + (w * 4 + qt) * 272 + lc;
#pragma unroll
        for (int r = 0; r < 4; ++r) dst[(quad * 4 + r) * 17] = a[r];   // stride 17: no 4-way conflict
      }
      __syncthreads();
      // wave w reduces tiles qt == w across the 4 strips
      const float4 sv4 = *(const float4*)(sufp + dktG * 16 + quad * 4);
      float v[4];
#pragma unroll
      for (int r = 0; r < 4; ++r) {
        const int e = (quad * 4 + r) * 17 + lc;
        v[r] = fbuf[(0 * 4 + w) * 272 + e] + fbuf[(1 * 4 + w) * 272 + e]
             + fbuf[(2 * 4 + w) * 272 + e] + fbuf[(3 * 4 + w) * 272 + e];
      }
      v[0] = (v[0] + sv4.x) * linv; v[1] = (v[1] + sv4.y) * linv;
      v[2] = (v[2] + sv4.z) * linv; v[3] = (v[3] + sv4.w) * linv;
      bf16x4 pk = { __float2bfloat16(v[0]), __float2bfloat16(v[1]),
                    __float2bfloat16(v[2]), __float2bfloat16(v[3]) };
      *(bf16x4*)(obuf + (w * 16 + lc) * 72 + dktG * 16 + quad * 4) = pk;
      __syncthreads();
    }

    // store: 2 instructions, each = 8 rows x 128B full lines
    const size_t obase = (size_t)(b * S_ + myqt * 64) * D_ + h * 64;
#pragma unroll
    for (int it = 0; it < 2; ++it) {
      const int idx = it * 256 + tid;
      const int row = idx >> 3, c8 = (idx & 7) * 8;
      const short8 vv = *(const short8*)(obuf + row * 72 + c8);
      *(short8*)(oa + obase + (size_t)row * D_ + c8) = vv;
    }
  }
}

extern "C" void kernel_launch(void* const* d_in, const int* in_sizes, int n_in,
                              void* d_out, int out_size, void* d_ws, size_t ws_size,
                              hipStream_t stream) {
  (void)in_sizes; (void)n_in; (void)out_size; (void)ws_size;
  const float* q_in = (const float*)d_in[0];
  const float* k_in = (const float*)d_in[1];
  const float* v_in = (const float*)d_in[2];
  const void*  pmask = d_in[3];
  const float* Wq = (const float*)d_in[4];
  const float* bq = (const float*)d_in[5];
  const float* Wk = (const float*)d_in[6];
  const float* bk = (const float*)d_in[7];
  const float* Wv = (const float*)d_in[8];
  const float* bv = (const float*)d_in[9];
  const float* Wo = (const float*)d_in[10];
  const float* bo = (const float*)d_in[11];

  char* ws = (char*)d_ws;
  bf16* xq  = (bf16*)(ws + 0);
  bf16* xk  = (bf16*)(ws + 8388608);
  bf16* xv  = (bf16*)(ws + 16777216);
  bf16* wqt = (bf16*)(ws + 25165824);
  bf16* wkt = (bf16*)(ws + 27262976);
  bf16* wvt = (bf16*)(ws + 29360128);
  bf16* wot = (bf16*)(ws + 31457280);
  bf16* qpp = (bf16*)(ws + 33554432);
  bf16* kpp = (bf16*)(ws + 41943040);
  bf16* vpp = (bf16*)(ws + 50331648);
  float* suf = (float*)(ws + 25165824);   // overlays wqt (dead after projections)
  int*  flg = (int*)(ws + 58720256);
  bf16* oa  = xq;

  prep_kernel<<<13313, 256, 0, stream>>>(q_in, k_in, v_in, Wq, Wk, Wv, Wo,
                                         xq, xk, xv, wqt, wkt, wvt, wot,
                                         (const unsigned int*)pmask, flg);

  gemm_k<128><<<dim3(8, 32, 3), 256, 0, stream>>>(xq, xk, xv, wqt, wkt, wvt,
                                                  bq, bk, bv, qpp, kpp, vpp, 0, D_, QSCALE);
  suf_kernel<<<32, 256, 0, stream>>>(vpp, suf);

  attn_kernel<<<512, 256, 0, stream>>>(qpp, kpp, vpp, suf, pmask, flg, oa);

  gemm_k<64><<<dim3(8, 64, 1), 256, 0, stream>>>(oa, oa, oa, wot, wot, wot,
                                                 bo, bo, bo, d_out, d_out, d_out, 2, D_, 1.f);
}

// Round 2
// 222.669 us; speedup vs baseline: 1.1215x; 1.1215x over previous
//
#include <hip/hip_runtime.h>
#include <hip/hip_bf16.h>
#include <cstdint>
#include <cstddef>

typedef __hip_bfloat16 bf16;
typedef __attribute__((ext_vector_type(8))) short short8;   // 8 bf16 = 4 VGPRs
typedef __attribute__((ext_vector_type(4))) short s4v;      // 4 bf16 = 2 VGPRs
typedef __attribute__((ext_vector_type(4))) float floatx4;

#define B_ 2
#define S_ 2048
#define D_ 1024
#define H_ 16
#define DK_ 64
#define M_ 4096
#define HEADELEMS 131072   // S_*DK_ per (b,h)
#define TILEELEMS 4096     // 64*64 per 64-token tile
#define QSCALE 0.1803368801111204f   // 0.125 * log2(e), folded into Q projection

struct __align__(8) bf16x4 { bf16 x, y, z, w; };

__device__ __forceinline__ floatx4 mfma16(short8 a, short8 b, floatx4 c) {
  return __builtin_amdgcn_mfma_f32_16x16x32_bf16(a, b, c, 0, 0, 0);
}
__device__ __forceinline__ void gl_lds16(const bf16* g, bf16* l) {
  __builtin_amdgcn_global_load_lds((const __attribute__((address_space(1))) void*)g,
                                   (__attribute__((address_space(3))) void*)l, 16, 0, 0);
}
__device__ __forceinline__ float bs2f(short s) {
  bf16 b = *reinterpret_cast<bf16*>(&s);
  return __bfloat162float(b);
}
__device__ __forceinline__ s4v pack4(float p0, float p1, float p2, float p3) {
  union { __hip_bfloat162 h; short2 s; } ua, ub;
  ua.h = __float22bfloat162_rn(make_float2(p0, p1));
  ub.h = __float22bfloat162_rn(make_float2(p2, p3));
  s4v r = {ua.s.x, ua.s.y, ub.s.x, ub.s.y};
  return r;
}
__device__ __forceinline__ float fast_exp2(float x) {
#if __has_builtin(__builtin_amdgcn_exp2f)
  return __builtin_amdgcn_exp2f(x);    // raw v_exp_f32 (no OCML range fixup)
#else
  float r; asm("v_exp_f32 %0, %1" : "=v"(r) : "v"(x)); return r;
#endif
}

// ---------------- fused prep: fp32->bf16 converts + weight transposes + mask detect ----------------
__global__ void prep_kernel(const float* __restrict__ q_in, const float* __restrict__ k_in,
                            const float* __restrict__ v_in,
                            const float* __restrict__ Wq, const float* __restrict__ Wk,
                            const float* __restrict__ Wv, const float* __restrict__ Wo,
                            bf16* __restrict__ xq, bf16* __restrict__ xk, bf16* __restrict__ xv,
                            bf16* __restrict__ wqt, bf16* __restrict__ wkt,
                            bf16* __restrict__ wvt, bf16* __restrict__ wot,
                            const unsigned int* __restrict__ pmask, int* __restrict__ flag) {
  __shared__ bf16 tile[64][66];
  __shared__ int sbyte;
  const int blk = blockIdx.x;
  const int tid = threadIdx.x;
  if (blk < 12288) {
    const int z = blk >> 12;
    const int i = ((blk & 4095) << 8) | tid;
    const float* src = (z == 0) ? q_in : (z == 1) ? k_in : v_in;
    bf16* dst = (z == 0) ? xq : (z == 1) ? xk : xv;
    float4 v = ((const float4*)src)[i];
    bf16x4 o = { __float2bfloat16(v.x), __float2bfloat16(v.y),
                 __float2bfloat16(v.z), __float2bfloat16(v.w) };
    ((bf16x4*)dst)[i] = o;
  } else if (blk < 13312) {
    const int t = blk - 12288;
    const int z = t >> 8;
    const int rc = t & 255;
    const int r0 = (rc >> 4) * 64, c0 = (rc & 15) * 64;
    const float* src = (z == 0) ? Wq : (z == 1) ? Wk : (z == 2) ? Wv : Wo;
    bf16* dst = (z == 0) ? wqt : (z == 1) ? wkt : (z == 2) ? wvt : wot;
    const int lr = tid >> 4;
    const int lc4 = (tid & 15) * 4;
#pragma unroll
    for (int i = 0; i < 4; ++i) {
      const int r = lr + i * 16;
      float4 v = *(const float4*)(src + (size_t)(r0 + r) * D_ + c0 + lc4);
      tile[r][lc4 + 0] = __float2bfloat16(v.x);
      tile[r][lc4 + 1] = __float2bfloat16(v.y);
      tile[r][lc4 + 2] = __float2bfloat16(v.z);
      tile[r][lc4 + 3] = __float2bfloat16(v.w);
    }
    __syncthreads();
    const int orr = tid & 63;
    const int oc0 = tid >> 6;
#pragma unroll
    for (int j = 0; j < 16; ++j) {
      const int oc = oc0 + j * 4;
      dst[(size_t)(c0 + oc) * D_ + r0 + orr] = tile[orr][oc];
    }
  } else {
    if (tid == 0) sbyte = 0;
    __syncthreads();
    for (int i = tid; i < (B_ * S_) / 4; i += 256) {
      const unsigned int v = pmask[i];
      if (((v & 0xFEFEFEFEu) == 0u) && ((v & 0xFFFFFF00u) != 0u)) sbyte = 1;
    }
    __syncthreads();
    if (tid == 0) *flag = sbyte;
  }
}

// ---------------- bf16 GEMM, C = A[M,K] * W[N,K]^T + bias ----------------
template<int MT>
__global__ __launch_bounds__(256, 2) void gemm_k(
    const bf16* __restrict__ A0, const bf16* __restrict__ A1, const bf16* __restrict__ A2,
    const bf16* __restrict__ W0, const bf16* __restrict__ W1, const bf16* __restrict__ W2,
    const float* __restrict__ b0, const float* __restrict__ b1, const float* __restrict__ b2,
    void* __restrict__ O0, void* __restrict__ O1, void* __restrict__ O2,
    const int mode01, const int Kd, const float sc)
{
  __shared__ __align__(16) bf16 sh[(MT + 128) * 32];   // As | Bs, contiguous
  bf16* As = sh;
  bf16* Bs = sh + MT * 32;
  const int z = blockIdx.z;
  const bf16* A = (z == 0) ? A0 : (z == 1) ? A1 : A2;
  const bf16* W = (z == 0) ? W0 : (z == 1) ? W1 : W2;
  const float* bias = (z == 0) ? b0 : (z == 1) ? b1 : b2;
  void* Cout = (z == 0) ? O0 : (z == 1) ? O1 : O2;
  const int mode = (z == 2) ? 1 : mode01;
  const float scz = (z == 0) ? sc : 1.f;

  constexpr int MI = MT / 32;
  const int tid = threadIdx.x;
  const int wave = tid >> 6, lane = tid & 63;
  const int quad = lane >> 4, lc = lane & 15;
  const int wm = (wave >> 1) * (MT / 2), wn = (wave & 1) * 64;
  const int m0 = blockIdx.y * MT, n0 = blockIdx.x * 128;

  const floatx4 zero4 = {0.f, 0.f, 0.f, 0.f};
  floatx4 acc[MI][4];
#pragma unroll
  for (int mi = 0; mi < MI; ++mi)
#pragma unroll
    for (int ni = 0; ni < 4; ++ni) acc[mi][ni] = zero4;

  const int ldr = lane >> 2;
  const int ldc = (lane & 3) * 8;
  const bf16* Ag = A + (size_t)(m0 + wave * (MT / 4) + ldr) * Kd + ldc;
  const bf16* Bg = W + (size_t)(n0 + wave * 32 + ldr) * Kd + ldc;
  bf16* As0 = As + wave * (MT / 4) * 32;
  bf16* Bs0 = Bs + wave * 32 * 32;

  for (int k0 = 0; k0 < Kd; k0 += 32) {
    gl_lds16(Ag + k0, As0);
    if (MT == 128) gl_lds16(Ag + k0 + (size_t)16 * Kd, As0 + 16 * 32);
    gl_lds16(Bg + k0, Bs0);
    gl_lds16(Bg + k0 + (size_t)16 * Kd, Bs0 + 16 * 32);
    __syncthreads();

    short8 af[MI], bfr[4];
#pragma unroll
    for (int i = 0; i < MI; ++i)
      af[i] = *(const short8*)(As + (wm + i * 16 + lc) * 32 + quad * 8);
#pragma unroll
    for (int i = 0; i < 4; ++i)
      bfr[i] = *(const short8*)(Bs + (wn + i * 16 + lc) * 32 + quad * 8);
#pragma unroll
    for (int mi = 0; mi < MI; ++mi)
#pragma unroll
      for (int ni = 0; ni < 4; ++ni)
        acc[mi][ni] = mfma16(af[mi], bfr[ni], acc[mi][ni]);
    __syncthreads();
  }

  if (mode == 2) {
    float* out = (float*)Cout;
#pragma unroll
    for (int mi = 0; mi < MI; ++mi)
#pragma unroll
      for (int ni = 0; ni < 4; ++ni) {
        const int col = n0 + wn + ni * 16 + lc;
        const float bv = bias[col];
        const int rbase = m0 + wm + mi * 16 + quad * 4;
#pragma unroll
        for (int r = 0; r < 4; ++r)
          out[(size_t)(rbase + r) * D_ + col] = acc[mi][ni][r] + bv;
      }
  } else {
    // LDS-bounce: this wave's 64x64 quadrant == one (T, head) swizzled tile.
    bf16* pool = sh + wave * 2048;
    float bvs[4];
#pragma unroll
    for (int ni = 0; ni < 4; ++ni) bvs[ni] = bias[n0 + wn + ni * 16 + lc];
    const int hcol = (n0 + wn) >> 6;
    const int mglob = m0 + wm;
    bf16* outb = (bf16*)Cout + (size_t)((mglob >> 11) * H_ + hcol) * HEADELEMS
               + (size_t)((mglob & (S_ - 1)) >> 6) * TILEELEMS;
#pragma unroll
    for (int half = 0; half < MI / 2; ++half) {
#pragma unroll
      for (int mi2 = 0; mi2 < 2; ++mi2) {
        const int mi = half * 2 + mi2;
#pragma unroll
        for (int ni = 0; ni < 4; ++ni) {
          const int dkl = ni * 16 + lc;
#pragma unroll
          for (int r = 0; r < 4; ++r) {
            const float v = (acc[mi][ni][r] + bvs[ni]) * scz;
            int idx;
            if (mode == 0) {
              const int c = (mi2 * 2 + (dkl >> 5)) * 64 + ((dkl >> 3) & 3) * 16 + quad * 4 + r;
              idx = c * 8 + (dkl & 7);
            } else {
              const int c = (mi2 * 4 + (dkl >> 4)) * 64 + quad * 16 + (dkl & 15);
              idx = c * 4 + r;
            }
            pool[idx] = __float2bfloat16(v);
          }
        }
      }
#pragma unroll
      for (int t = 0; t < 4; ++t) {
        const short8 vv = *(const short8*)(pool + t * 512 + lane * 8);
        *(short8*)(outb + half * 2048 + t * 512 + lane * 8) = vv;
      }
    }
  }
}

// ---------------- V suffix sums ----------------
__global__ void suf_kernel(const bf16* __restrict__ vp, float* __restrict__ suf) {
  __shared__ float ts[32 * 64];
  const int bhid = blockIdx.x;
  const bf16* vb = vp + (size_t)bhid * HEADELEMS;
  const int tid = threadIdx.x;
  const int dk = tid & 63, g = tid >> 6;
  const int dkt = dk >> 4, lck = dk & 15;
  for (int T = g * 8; T < g * 8 + 8; ++T) {
    float sum = 0.f;
#pragma unroll
    for (int w = 0; w < 4; ++w)
#pragma unroll
      for (int qd = 0; qd < 4; ++qd) {
        const s4v x = *(const s4v*)(vb + (size_t)T * TILEELEMS
                                    + (size_t)(((w * 4 + dkt) * 64 + qd * 16 + lck)) * 4);
        sum += bs2f(x[0]) + bs2f(x[1]) + bs2f(x[2]) + bs2f(x[3]);
      }
    ts[T * 64 + dk] = sum;
  }
  __syncthreads();
  if (g == 0) {
    float run = 0.f;
    float* out = suf + (size_t)bhid * (33 * 64);
    out[32 * 64 + dk] = 0.f;
    for (int T = 31; T >= 0; --T) { run += ts[T * 64 + dk]; out[T * 64 + dk] = run; }
  }
}

// ---------------- fused attention ----------------
// S^T = K*Q^T for one 64-key tile (wave owns 16-key strip); mask+exp -> pf (P^T, B-frag-ready)
// Pad mask comes from a precomputed per-lane 32-tile bitmask (no memory access in-loop).
template<bool DIAGP>
__device__ __forceinline__ void qk_tile(const short8 ak0, const short8 ak1,
                                        const short8 (&qf)[4][2],
                                        const unsigned int (&pmb)[4], const int T,
                                        float (&lacc)[4], s4v (&pf)[4],
                                        const int w, const int quad, const int lc,
                                        const bool diag) {
  const floatx4 z4 = {0.f, 0.f, 0.f, 0.f};
  const short ONE = (short)0x3F80;
#pragma unroll
  for (int qt = 0; qt < 4; ++qt) {
    if (DIAGP && diag && w > qt) { // strictly-upper 16x16 subtile: all masked -> p = 1
      s4v o1 = {ONE, ONE, ONE, ONE};
      pf[qt] = o1;
      lacc[qt] += 4.f;
      continue;
    }
    floatx4 s = mfma16(ak0, qf[qt][0], z4);
    s = mfma16(ak1, qf[qt][1], s);
    float pv[4];
#pragma unroll
    for (int r = 0; r < 4; ++r) {
      bool m = ((pmb[r] >> T) & 1u) != 0u;
      if (DIAGP && diag && w == qt) m = m || (quad * 4 + r > lc);
      pv[r] = fast_exp2(m ? 0.f : s[r]);
      lacc[qt] += pv[r];
    }
    pf[qt] = pack4(pv[0], pv[1], pv[2], pv[3]);
  }
}

__device__ __forceinline__ void pv_step(const s4v (&va0)[4], const s4v (&va1)[4],
                                        const s4v (&pf0)[4], const s4v (&pf1)[4],
                                        floatx4 (&oacc)[4][4]) {
  short8 pB[4];
#pragma unroll
  for (int qt = 0; qt < 4; ++qt)
    pB[qt] = __builtin_shufflevector(pf0[qt], pf1[qt], 0, 1, 2, 3, 4, 5, 6, 7);
#pragma unroll
  for (int dkt = 0; dkt < 4; ++dkt) {
    const short8 av = __builtin_shufflevector(va0[dkt], va1[dkt], 0, 1, 2, 3, 4, 5, 6, 7);
#pragma unroll
    for (int qt = 0; qt < 4; ++qt)
      oacc[dkt][qt] = mfma16(av, pB[qt], oacc[dkt][qt]);
  }
}

// Stage one p-step (K tiles T0,T1 + V tiles T0,T1 = 32KB/block) into an LDS slot.
// Each wave stages EXACTLY the 8KB it will consume -> zero cross-wave deps in the
// main loop (no barriers). global_load_lds: no VGPR destinations -> no register-
// pressure load serialization; counted vmcnt keeps the pipe full (T3/T4 pattern).
// Slot layout (bf16 elems): [K_T0 0..4096) [K_T1 4096..8192) [V_T0 8192..12288) [V_T1 12288..16384)
__device__ __forceinline__ void stage8(const bf16* kb, const bf16* vb, bf16* slot,
                                       const int T0, const int T1,
                                       const int wl, const int wreg) {
  const bf16* k0 = kb + (size_t)T0 * TILEELEMS + wl;
  const bf16* k1 = kb + (size_t)T1 * TILEELEMS + wl;
  const bf16* v0 = vb + (size_t)T0 * TILEELEMS + wl;
  const bf16* v1 = vb + (size_t)T1 * TILEELEMS + wl;
  gl_lds16(k0,       slot + wreg);
  gl_lds16(k0 + 512, slot + wreg + 512);
  gl_lds16(k1,       slot + 4096 + wreg);
  gl_lds16(k1 + 512, slot + 4096 + wreg + 512);
  gl_lds16(v0,       slot + 8192 + wreg);
  gl_lds16(v0 + 512, slot + 8192 + wreg + 512);
  gl_lds16(v1,       slot + 12288 + wreg);
  gl_lds16(v1 + 512, slot + 12288 + wreg + 512);
}

// Main loop: LDS double-buffered K/V via global_load_lds, one counted s_waitcnt
// vmcnt(8) per step (waits only for the PREVIOUS step's stages), no barriers, no
// VGPR-destination VMEM in-loop. Each block owns the uniform q-tile pair (31-j, j)
// = exactly 17 p-steps. Grid 512 (2 blocks/CU), lin&7 = XCD = bh&7 for L2 locality.
__global__ __launch_bounds__(256, 1) void attn_kernel(
    const bf16* __restrict__ qp, const bf16* __restrict__ kp,
    const bf16* __restrict__ vp, const float* __restrict__ suf,
    const void* __restrict__ pad, const int* __restrict__ flag,
    bf16* __restrict__ oa)
{
  // 64KB: two 32KB staging slots; epilogue fbuf/obuf/lbuf aliased into slot 0.
  __shared__ __align__(16) bf16 lds[32768];

  const int lin = blockIdx.x;          // 512 blocks
  const int xcd = lin & 7;
  const int t = lin >> 3;              // 0..63
  const int grp = t >> 4;              // 0..3
  const int jq = t & 15;               // q-pair (31-jq, jq): p-steps sum to 17 for all jq
  const int bh = xcd + 8 * grp;
  const int b = bh >> 4, h = bh & 15;

  const int tid = threadIdx.x;
  const int w = tid >> 6, lane = tid & 63, quad = lane >> 4, lc = lane & 15;
  const int bytemode = *flag;

  const int wreg = w * 1024;           // wave-uniform elem offset of this wave's region
  const int wl = wreg + lane * 8;      // per-lane elem offset (16B chunks)
  const int vl = wreg + lane * 4;      // per-lane V-frag elem offset (8B)

  const bf16* kb = kp + (size_t)bh * HEADELEMS;
  const bf16* vb = vp + (size_t)bh * HEADELEMS;

  // ---- precompute pad mask bitmask: pmb[r] bit T = pad[b][T*64 + w*16 + quad*4 + r] ----
  unsigned int pmb[4] = {0u, 0u, 0u, 0u};
  if (bytemode) {
    const unsigned char* pp = (const unsigned char*)pad + b * S_ + w * 16 + quad * 4;
#pragma unroll
    for (int T = 0; T < 32; ++T) {
      const uchar4 u = *(const uchar4*)(pp + T * 64);
      pmb[0] |= (u.x ? 1u : 0u) << T;
      pmb[1] |= (u.y ? 1u : 0u) << T;
      pmb[2] |= (u.z ? 1u : 0u) << T;
      pmb[3] |= (u.w ? 1u : 0u) << T;
    }
  } else {
    const int* pp = (const int*)pad + b * S_ + w * 16 + quad * 4;
#pragma unroll
    for (int T = 0; T < 32; ++T) {
      const int4 u = *(const int4*)(pp + (size_t)T * 64);
      pmb[0] |= (u.x ? 1u : 0u) << T;
      pmb[1] |= (u.y ? 1u : 0u) << T;
      pmb[2] |= (u.z ? 1u : 0u) << T;
      pmb[3] |= (u.w ? 1u : 0u) << T;
    }
  }

#pragma unroll 1
  for (int qsel = 0; qsel < 2; ++qsel) {
    const int myqt = qsel ? jq : 31 - jq;
    const int mynt = myqt + 1;
    const int np = (mynt + 1) >> 1;    // p-steps (2 key-tiles each)

    // ---- prologue: stage Q (8KB, cross-wave shared) into slot1's K_T0 area,
    //      stage p-step 0 into slot 0; drain; barrier; read Q frags; barrier. ----
    const bf16* qb = qp + (size_t)bh * HEADELEMS + (size_t)myqt * TILEELEMS;
    gl_lds16(qb + wl,       lds + 16384 + wreg);
    gl_lds16(qb + wl + 512, lds + 16384 + wreg + 512);
    stage8(kb, vb, lds, 0, 1, wl, wreg);
    asm volatile("s_waitcnt vmcnt(0)" ::: "memory");
    __syncthreads();

    short8 qf[4][2];
#pragma unroll
    for (int qt = 0; qt < 4; ++qt)
#pragma unroll
      for (int hh = 0; hh < 2; ++hh)
        qf[qt][hh] = *(const short8*)(lds + 16384 + qt * 1024 + hh * 512 + lane * 8);
    __syncthreads();   // qf in regs before stage(1) overwrites slot1

    const floatx4 zero4 = {0.f, 0.f, 0.f, 0.f};
    floatx4 oacc[4][4];                            // [dkt][qt]
#pragma unroll
    for (int i = 0; i < 4; ++i)
#pragma unroll
      for (int jj = 0; jj < 4; ++jj) oacc[i][jj] = zero4;
    float lacc[4] = {0.f, 0.f, 0.f, 0.f};

#pragma unroll 1
    for (int p = 0; p < np; ++p) {
      if (p + 1 < np) {
        stage8(kb, vb, lds + (((p + 1) & 1) << 14), 2 * p + 2, 2 * p + 3, wl, wreg);
        asm volatile("s_waitcnt vmcnt(8)" ::: "memory");   // wait for step p's stages only
      } else {
        asm volatile("s_waitcnt vmcnt(0)" ::: "memory");
      }
      __builtin_amdgcn_sched_barrier(0);

      bf16* slot = lds + ((p & 1) << 14);
      const short8 ak00 = *(const short8*)(slot + wl);
      const short8 ak01 = *(const short8*)(slot + wl + 512);
      const short8 ak10 = *(const short8*)(slot + 4096 + wl);
      const short8 ak11 = *(const short8*)(slot + 4096 + wl + 512);
      s4v va0[4], va1[4];
#pragma unroll
      for (int dkt = 0; dkt < 4; ++dkt) {
        va0[dkt] = *(const s4v*)(slot + 8192 + vl + dkt * 256);
        va1[dkt] = *(const s4v*)(slot + 12288 + vl + dkt * 256);
      }

      const int T0 = 2 * p, T1 = 2 * p + 1;
      s4v pf0[4], pf1[4];
      if (p + 1 < np) {
        qk_tile<false>(ak00, ak01, qf, pmb, T0, lacc, pf0, w, quad, lc, false);
        qk_tile<false>(ak10, ak11, qf, pmb, T1, lacc, pf1, w, quad, lc, false);
      } else {  // tail step: contains the diagonal tile (and phantom T1 when mynt odd)
        qk_tile<true>(ak00, ak01, qf, pmb, T0, lacc, pf0, w, quad, lc, T0 == mynt - 1);
        if (T1 < mynt) {
          qk_tile<true>(ak10, ak11, qf, pmb, T1, lacc, pf1, w, quad, lc, true);
        } else {
          const s4v zz = {0, 0, 0, 0};
#pragma unroll
          for (int qt = 0; qt < 4; ++qt) pf1[qt] = zz;   // phantom: covered by suffix sums
        }
      }
      pv_step(va0, va1, pf0, pf1, oacc);
    }

    __syncthreads();   // all waves out of the staging slots before epilogue aliases them

    // ---- epilogue: cross-strip reduction -> LDS out-tile -> full-128B-line stores ----
    // Aliased into slot 0: fbuf bytes [0,17408), obuf [17408,26624), lbuf [26624,27648).
    float* fbuf = (float*)lds;
    bf16* obuf = lds + 8704;
    float* lbuf = (float*)(lds + 13312);

#pragma unroll
    for (int qt = 0; qt < 4; ++qt) {
      float v = lacc[qt];
      v += __shfl_xor(v, 16);
      v += __shfl_xor(v, 32);
      if (quad == 0) lbuf[w * 64 + qt * 16 + lc] = v;
    }
    __syncthreads();
    float ls = lbuf[0 * 64 + w * 16 + lc] + lbuf[1 * 64 + w * 16 + lc]
             + lbuf[2 * 64 + w * 16 + lc] + lbuf[3 * 64 + w * 16 + lc];
    ls += (float)(S_ - mynt * 64);                 // keys past diagonal tile: weight 1 each
    const float linv = 1.f / ls;
    const float* sufp = suf + (size_t)bh * (33 * 64) + mynt * 64;

#pragma unroll
    for (int dktG = 0; dktG < 4; ++dktG) {
#pragma unroll
      for (int qt = 0; qt < 4; ++qt) {
        const floatx4 a = oacc[dktG][qt];
        float* dst = fbuf + (w * 4 + qt) * 272 + lc;
#pragma unroll
        for (int r = 0; r < 4; ++r) dst[(quad * 4 + r) * 17] = a[r];   // stride 17: conflict-free
      }
      __syncthreads();
      // wave w reduces tiles qt == w across the 4 strips
      const float4 sv4 = *(const float4*)(sufp + dktG * 16 + quad * 4);
      float v[4];
#pragma unroll
      for (int r = 0; r < 4; ++r) {
        const int e = (quad * 4 + r) * 17 + lc;
        v[r] = fbuf[(0 * 4 + w) * 272 + e] + fbuf[(1 * 4 + w) * 272 + e]
             + fbuf[(2 * 4 + w) * 272 + e] + fbuf[(3 * 4 + w) * 272 + e];
      }
      v[0] = (v[0] + sv4.x) * linv; v[1] = (v[1] + sv4.y) * linv;
      v[2] = (v[2] + sv4.z) * linv; v[3] = (v[3] + sv4.w) * linv;
      bf16x4 pk = { __float2bfloat16(v[0]), __float2bfloat16(v[1]),
                    __float2bfloat16(v[2]), __float2bfloat16(v[3]) };
      *(bf16x4*)(obuf + (w * 16 + lc) * 72 + dktG * 16 + quad * 4) = pk;
      __syncthreads();
    }

    // store: 2 instructions, each = 8 rows x 128B full lines
    const size_t obase = (size_t)(b * S_ + myqt * 64) * D_ + h * 64;
#pragma unroll
    for (int it = 0; it < 2; ++it) {
      const int idx = it * 256 + tid;
      const int row = idx >> 3, c8 = (idx & 7) * 8;
      const short8 vv = *(const short8*)(obuf + row * 72 + c8);
      *(short8*)(oa + obase + (size_t)row * D_ + c8) = vv;
    }
    __syncthreads();   // epilogue LDS dead before next qsel's staging reuses it
  }
}

extern "C" void kernel_launch(void* const* d_in, const int* in_sizes, int n_in,
                              void* d_out, int out_size, void* d_ws, size_t ws_size,
                              hipStream_t stream) {
  (void)in_sizes; (void)n_in; (void)out_size; (void)ws_size;
  const float* q_in = (const float*)d_in[0];
  const float* k_in = (const float*)d_in[1];
  const float* v_in = (const float*)d_in[2];
  const void*  pmask = d_in[3];
  const float* Wq = (const float*)d_in[4];
  const float* bq = (const float*)d_in[5];
  const float* Wk = (const float*)d_in[6];
  const float* bk = (const float*)d_in[7];
  const float* Wv = (const float*)d_in[8];
  const float* bv = (const float*)d_in[9];
  const float* Wo = (const float*)d_in[10];
  const float* bo = (const float*)d_in[11];

  char* ws = (char*)d_ws;
  bf16* xq  = (bf16*)(ws + 0);
  bf16* xk  = (bf16*)(ws + 8388608);
  bf16* xv  = (bf16*)(ws + 16777216);
  bf16* wqt = (bf16*)(ws + 25165824);
  bf16* wkt = (bf16*)(ws + 27262976);
  bf16* wvt = (bf16*)(ws + 29360128);
  bf16* wot = (bf16*)(ws + 31457280);
  bf16* qpp = (bf16*)(ws + 33554432);
  bf16* kpp = (bf16*)(ws + 41943040);
  bf16* vpp = (bf16*)(ws + 50331648);
  float* suf = (float*)(ws + 25165824);   // overlays wqt (dead after projections)
  int*  flg = (int*)(ws + 58720256);
  bf16* oa  = xq;

  prep_kernel<<<13313, 256, 0, stream>>>(q_in, k_in, v_in, Wq, Wk, Wv, Wo,
                                         xq, xk, xv, wqt, wkt, wvt, wot,
                                         (const unsigned int*)pmask, flg);

  gemm_k<128><<<dim3(8, 32, 3), 256, 0, stream>>>(xq, xk, xv, wqt, wkt, wvt,
                                                  bq, bk, bv, qpp, kpp, vpp, 0, D_, QSCALE);
  suf_kernel<<<32, 256, 0, stream>>>(vpp, suf);

  attn_kernel<<<512, 256, 0, stream>>>(qpp, kpp, vpp, suf, pmask, flg, oa);

  gemm_k<64><<<dim3(8, 64, 1), 256, 0, stream>>>(oa, oa, oa, wot, wot, wot,
                                                 bo, bo, bo, d_out, d_out, d_out, 2, D_, 1.f);
}

// Round 3
// 216.258 us; speedup vs baseline: 1.1548x; 1.0296x over previous
//
#include <hip/hip_runtime.h>
#include <hip/hip_bf16.h>
#include <cstdint>
#include <cstddef>

typedef __hip_bfloat16 bf16;
typedef __attribute__((ext_vector_type(8))) short short8;   // 8 bf16 = 4 VGPRs
typedef __attribute__((ext_vector_type(4))) short s4v;      // 4 bf16 = 2 VGPRs
typedef __attribute__((ext_vector_type(4))) float floatx4;

#define B_ 2
#define S_ 2048
#define D_ 1024
#define H_ 16
#define DK_ 64
#define M_ 4096
#define HEADELEMS 131072   // S_*DK_ per (b,h)
#define TILEELEMS 4096     // 64*64 per 64-token tile
#define QSCALE 0.1803368801111204f   // 0.125 * log2(e), folded into Q projection

struct __align__(8) bf16x4 { bf16 x, y, z, w; };

__device__ __forceinline__ floatx4 mfma16(short8 a, short8 b, floatx4 c) {
  return __builtin_amdgcn_mfma_f32_16x16x32_bf16(a, b, c, 0, 0, 0);
}
__device__ __forceinline__ void gl_lds16(const bf16* g, bf16* l) {
  __builtin_amdgcn_global_load_lds((const __attribute__((address_space(1))) void*)g,
                                   (__attribute__((address_space(3))) void*)l, 16, 0, 0);
}
__device__ __forceinline__ float bs2f(short s) {
  bf16 b = *reinterpret_cast<bf16*>(&s);
  return __bfloat162float(b);
}
__device__ __forceinline__ s4v pack4(float p0, float p1, float p2, float p3) {
  union { __hip_bfloat162 h; short2 s; } ua, ub;
  ua.h = __float22bfloat162_rn(make_float2(p0, p1));
  ub.h = __float22bfloat162_rn(make_float2(p2, p3));
  s4v r = {ua.s.x, ua.s.y, ub.s.x, ub.s.y};
  return r;
}
__device__ __forceinline__ float fast_exp2(float x) {
#if __has_builtin(__builtin_amdgcn_exp2f)
  return __builtin_amdgcn_exp2f(x);    // raw v_exp_f32 (no OCML range fixup)
#else
  float r; asm("v_exp_f32 %0, %1" : "=v"(r) : "v"(x)); return r;
#endif
}

// ---------------- fused prep: fp32->bf16 converts + weight transposes + mask detect ----------------
__global__ void prep_kernel(const float* __restrict__ q_in, const float* __restrict__ k_in,
                            const float* __restrict__ v_in,
                            const float* __restrict__ Wq, const float* __restrict__ Wk,
                            const float* __restrict__ Wv, const float* __restrict__ Wo,
                            bf16* __restrict__ xq, bf16* __restrict__ xk, bf16* __restrict__ xv,
                            bf16* __restrict__ wqt, bf16* __restrict__ wkt,
                            bf16* __restrict__ wvt, bf16* __restrict__ wot,
                            const unsigned int* __restrict__ pmask, int* __restrict__ flag) {
  __shared__ bf16 tile[64][66];
  __shared__ int sbyte;
  const int blk = blockIdx.x;
  const int tid = threadIdx.x;
  if (blk < 12288) {
    const int z = blk >> 12;
    const int i = ((blk & 4095) << 8) | tid;
    const float* src = (z == 0) ? q_in : (z == 1) ? k_in : v_in;
    bf16* dst = (z == 0) ? xq : (z == 1) ? xk : xv;
    float4 v = ((const float4*)src)[i];
    bf16x4 o = { __float2bfloat16(v.x), __float2bfloat16(v.y),
                 __float2bfloat16(v.z), __float2bfloat16(v.w) };
    ((bf16x4*)dst)[i] = o;
  } else if (blk < 13312) {
    const int t = blk - 12288;
    const int z = t >> 8;
    const int rc = t & 255;
    const int r0 = (rc >> 4) * 64, c0 = (rc & 15) * 64;
    const float* src = (z == 0) ? Wq : (z == 1) ? Wk : (z == 2) ? Wv : Wo;
    bf16* dst = (z == 0) ? wqt : (z == 1) ? wkt : (z == 2) ? wvt : wot;
    const int lr = tid >> 4;
    const int lc4 = (tid & 15) * 4;
#pragma unroll
    for (int i = 0; i < 4; ++i) {
      const int r = lr + i * 16;
      float4 v = *(const float4*)(src + (size_t)(r0 + r) * D_ + c0 + lc4);
      tile[r][lc4 + 0] = __float2bfloat16(v.x);
      tile[r][lc4 + 1] = __float2bfloat16(v.y);
      tile[r][lc4 + 2] = __float2bfloat16(v.z);
      tile[r][lc4 + 3] = __float2bfloat16(v.w);
    }
    __syncthreads();
    const int orr = tid & 63;
    const int oc0 = tid >> 6;
#pragma unroll
    for (int j = 0; j < 16; ++j) {
      const int oc = oc0 + j * 4;
      dst[(size_t)(c0 + oc) * D_ + r0 + orr] = tile[orr][oc];
    }
  } else {
    if (tid == 0) sbyte = 0;
    __syncthreads();
    for (int i = tid; i < (B_ * S_) / 4; i += 256) {
      const unsigned int v = pmask[i];
      if (((v & 0xFEFEFEFEu) == 0u) && ((v & 0xFFFFFF00u) != 0u)) sbyte = 1;
    }
    __syncthreads();
    if (tid == 0) *flag = sbyte;
  }
}

// ---------------- bf16 GEMM, C = A[M,K] * W[N,K]^T + bias ----------------
// BK=64 (128B LDS rows = bank cycle), XOR-swizzled staging (chunk ^= row&7) via
// pre-swizzled global_load_lds SOURCE addresses -> 2-way (free) ds_read_b128.
// Double-buffered 2-phase loop: stage(k+1) || ds_read+MFMA(k), one barrier/step.
// Grid (Mtiles, Ntiles, z): blockIdx.x = m-tile so the 8 blocks sharing an
// A-panel land on ONE XCD (lin%8 == bx%8) -> A-panel L2-local, no 8x over-fetch.
// mode 0: bf16 out, Q/K fragment-swizzled per-head tiles; mode 1: V^T tiles;
// mode 2: fp32 out, plain [M][N]
template<int MT>
__global__ __launch_bounds__(256, 2) void gemm_k(
    const bf16* __restrict__ A0, const bf16* __restrict__ A1, const bf16* __restrict__ A2,
    const bf16* __restrict__ W0, const bf16* __restrict__ W1, const bf16* __restrict__ W2,
    const float* __restrict__ b0, const float* __restrict__ b1, const float* __restrict__ b2,
    void* __restrict__ O0, void* __restrict__ O1, void* __restrict__ O2,
    const int mode01, const int Kd, const float sc)
{
  constexpr int ROWS = MT + 128;                    // A rows + B rows
  __shared__ __align__(16) bf16 sh[2 * ROWS * 64];  // two BK=64 buffers (64KB at MT=128)
  const int z = blockIdx.z;
  const bf16* A = (z == 0) ? A0 : (z == 1) ? A1 : A2;
  const bf16* W = (z == 0) ? W0 : (z == 1) ? W1 : W2;
  const float* bias = (z == 0) ? b0 : (z == 1) ? b1 : b2;
  void* Cout = (z == 0) ? O0 : (z == 1) ? O1 : O2;
  const int mode = (z == 2) ? 1 : mode01;
  const float scz = (z == 0) ? sc : 1.f;

  constexpr int MI = MT / 32;
  const int tid = threadIdx.x;
  const int wave = tid >> 6, lane = tid & 63;
  const int quad = lane >> 4, lc = lane & 15;
  const int wm = (wave >> 1) * (MT / 2), wn = (wave & 1) * 64;
  const int m0 = blockIdx.x * MT, n0 = blockIdx.y * 128;

  const floatx4 zero4 = {0.f, 0.f, 0.f, 0.f};
  floatx4 acc[MI][4];
#pragma unroll
  for (int mi = 0; mi < MI; ++mi)
#pragma unroll
    for (int ni = 0; ni < 4; ++ni) acc[mi][ni] = zero4;

  // staging: each gl_lds op = 64 lanes x 16B = 8 rows of 128B. Lane covers
  // (row = base + lane>>3, physical chunk = lane&7); source fetches LOGICAL
  // chunk (lane&7)^(lane>>3) so that LDS[row][c'] = global[row][c'^(row&7)].
  const int srow = lane >> 3;
  const int schunk = ((lane & 7) ^ srow) * 8;       // elems
  const bf16* Ag = A + (size_t)(m0 + wave * (MT / 4) + srow) * Kd + schunk;
  const bf16* Bg = W + (size_t)(n0 + wave * 32 + srow) * Kd + schunk;

  auto stage = [&](bf16* buf, int k0) {
    bf16* As0 = buf + wave * (MT / 4) * 64;
    bf16* Bs0 = buf + MT * 64 + wave * 32 * 64;
#pragma unroll
    for (int j = 0; j < MT / 32; ++j)
      gl_lds16(Ag + k0 + (size_t)(j * 8) * Kd, As0 + j * 512);
#pragma unroll
    for (int j = 0; j < 4; ++j)
      gl_lds16(Bg + k0 + (size_t)(j * 8) * Kd, Bs0 + j * 512);
  };

  stage(sh, 0);
  asm volatile("s_waitcnt vmcnt(0)" ::: "memory");
  __syncthreads();

  int cur = 0;
  for (int k0 = 0; k0 < Kd; k0 += 64) {
    bf16* cbuf = cur ? sh + ROWS * 64 : sh;
    bf16* nbuf = cur ? sh : sh + ROWS * 64;
    const bool more = (k0 + 64 < Kd);
    if (more) stage(nbuf, k0 + 64);                 // prefetch: hidden under reads+MFMA

    const bf16* Ar = cbuf;
    const bf16* Br = cbuf + MT * 64;
    short8 af[2][MI], bfr[2][4];
#pragma unroll
    for (int kk = 0; kk < 2; ++kk) {
#pragma unroll
      for (int i = 0; i < MI; ++i)
        af[kk][i] = *(const short8*)(Ar + (wm + i * 16 + lc) * 64
                                     + (((kk * 4 + quad) ^ (lc & 7)) * 8));
#pragma unroll
      for (int i = 0; i < 4; ++i)
        bfr[kk][i] = *(const short8*)(Br + (wn + i * 16 + lc) * 64
                                      + (((kk * 4 + quad) ^ (lc & 7)) * 8));
    }
#pragma unroll
    for (int kk = 0; kk < 2; ++kk)
#pragma unroll
      for (int mi = 0; mi < MI; ++mi)
#pragma unroll
        for (int ni = 0; ni < 4; ++ni)
          acc[mi][ni] = mfma16(af[kk][mi], bfr[kk][ni], acc[mi][ni]);

    __syncthreads();   // drains vmcnt(0): next buffer staged, this buffer free
    cur ^= 1;
  }

  if (mode == 2) {
    float* out = (float*)Cout;
#pragma unroll
    for (int mi = 0; mi < MI; ++mi)
#pragma unroll
      for (int ni = 0; ni < 4; ++ni) {
        const int col = n0 + wn + ni * 16 + lc;
        const float bv = bias[col];
        const int rbase = m0 + wm + mi * 16 + quad * 4;
#pragma unroll
        for (int r = 0; r < 4; ++r)
          out[(size_t)(rbase + r) * D_ + col] = acc[mi][ni][r] + bv;
      }
  } else {
    // LDS-bounce: this wave's 64x64 quadrant == one (T, head) swizzled tile.
    bf16* pool = sh + wave * 2048;
    float bvs[4];
#pragma unroll
    for (int ni = 0; ni < 4; ++ni) bvs[ni] = bias[n0 + wn + ni * 16 + lc];
    const int hcol = (n0 + wn) >> 6;
    const int mglob = m0 + wm;
    bf16* outb = (bf16*)Cout + (size_t)((mglob >> 11) * H_ + hcol) * HEADELEMS
               + (size_t)((mglob & (S_ - 1)) >> 6) * TILEELEMS;
#pragma unroll
    for (int half = 0; half < MI / 2; ++half) {
#pragma unroll
      for (int mi2 = 0; mi2 < 2; ++mi2) {
        const int mi = half * 2 + mi2;
#pragma unroll
        for (int ni = 0; ni < 4; ++ni) {
          const int dkl = ni * 16 + lc;
#pragma unroll
          for (int r = 0; r < 4; ++r) {
            const float v = (acc[mi][ni][r] + bvs[ni]) * scz;
            int idx;
            if (mode == 0) {
              const int c = (mi2 * 2 + (dkl >> 5)) * 64 + ((dkl >> 3) & 3) * 16 + quad * 4 + r;
              idx = c * 8 + (dkl & 7);
            } else {
              const int c = (mi2 * 4 + (dkl >> 4)) * 64 + quad * 16 + (dkl & 15);
              idx = c * 4 + r;
            }
            pool[idx] = __float2bfloat16(v);
          }
        }
      }
#pragma unroll
      for (int t = 0; t < 4; ++t) {
        const short8 vv = *(const short8*)(pool + t * 512 + lane * 8);
        *(short8*)(outb + half * 2048 + t * 512 + lane * 8) = vv;
      }
    }
  }
}

// ---------------- V suffix sums ----------------
__global__ void suf_kernel(const bf16* __restrict__ vp, float* __restrict__ suf) {
  __shared__ float ts[32 * 64];
  const int bhid = blockIdx.x;
  const bf16* vb = vp + (size_t)bhid * HEADELEMS;
  const int tid = threadIdx.x;
  const int dk = tid & 63, g = tid >> 6;
  const int dkt = dk >> 4, lck = dk & 15;
  for (int T = g * 8; T < g * 8 + 8; ++T) {
    float sum = 0.f;
#pragma unroll
    for (int w = 0; w < 4; ++w)
#pragma unroll
      for (int qd = 0; qd < 4; ++qd) {
        const s4v x = *(const s4v*)(vb + (size_t)T * TILEELEMS
                                    + (size_t)(((w * 4 + dkt) * 64 + qd * 16 + lck)) * 4);
        sum += bs2f(x[0]) + bs2f(x[1]) + bs2f(x[2]) + bs2f(x[3]);
      }
    ts[T * 64 + dk] = sum;
  }
  __syncthreads();
  if (g == 0) {
    float run = 0.f;
    float* out = suf + (size_t)bhid * (33 * 64);
    out[32 * 64 + dk] = 0.f;
    for (int T = 31; T >= 0; --T) { run += ts[T * 64 + dk]; out[T * 64 + dk] = run; }
  }
}

// ---------------- fused attention ----------------
// S^T = K*Q^T for one 64-key tile (wave owns 16-key strip); mask+exp -> pf (P^T, B-frag-ready)
// Pad mask comes from a precomputed per-lane 32-tile bitmask (no memory access in-loop).
template<bool DIAGP>
__device__ __forceinline__ void qk_tile(const short8 ak0, const short8 ak1,
                                        const short8 (&qf)[4][2],
                                        const unsigned int (&pmb)[4], const int T,
                                        float (&lacc)[4], s4v (&pf)[4],
                                        const int w, const int quad, const int lc,
                                        const bool diag) {
  const floatx4 z4 = {0.f, 0.f, 0.f, 0.f};
  const short ONE = (short)0x3F80;
#pragma unroll
  for (int qt = 0; qt < 4; ++qt) {
    if (DIAGP && diag && w > qt) { // strictly-upper 16x16 subtile: all masked -> p = 1
      s4v o1 = {ONE, ONE, ONE, ONE};
      pf[qt] = o1;
      lacc[qt] += 4.f;
      continue;
    }
    floatx4 s = mfma16(ak0, qf[qt][0], z4);
    s = mfma16(ak1, qf[qt][1], s);
    float pv[4];
#pragma unroll
    for (int r = 0; r < 4; ++r) {
      bool m = ((pmb[r] >> T) & 1u) != 0u;
      if (DIAGP && diag && w == qt) m = m || (quad * 4 + r > lc);
      pv[r] = fast_exp2(m ? 0.f : s[r]);
      lacc[qt] += pv[r];
    }
    pf[qt] = pack4(pv[0], pv[1], pv[2], pv[3]);
  }
}

__device__ __forceinline__ void pv_step(const s4v (&va0)[4], const s4v (&va1)[4],
                                        const s4v (&pf0)[4], const s4v (&pf1)[4],
                                        floatx4 (&oacc)[4][4]) {
  short8 pB[4];
#pragma unroll
  for (int qt = 0; qt < 4; ++qt)
    pB[qt] = __builtin_shufflevector(pf0[qt], pf1[qt], 0, 1, 2, 3, 4, 5, 6, 7);
#pragma unroll
  for (int dkt = 0; dkt < 4; ++dkt) {
    const short8 av = __builtin_shufflevector(va0[dkt], va1[dkt], 0, 1, 2, 3, 4, 5, 6, 7);
#pragma unroll
    for (int qt = 0; qt < 4; ++qt)
      oacc[dkt][qt] = mfma16(av, pB[qt], oacc[dkt][qt]);
  }
}

// Stage one p-step (K tiles T0,T1 + V tiles T0,T1 = 32KB/block) into an LDS slot.
// Each wave stages EXACTLY the 8KB it will consume -> zero cross-wave deps in the
// main loop (no barriers). global_load_lds: no VGPR destinations -> no register-
// pressure load serialization; counted vmcnt keeps the pipe full (T3/T4 pattern).
// Slot layout (bf16 elems): [K_T0 0..4096) [K_T1 4096..8192) [V_T0 8192..12288) [V_T1 12288..16384)
__device__ __forceinline__ void stage8(const bf16* kb, const bf16* vb, bf16* slot,
                                       const int T0, const int T1,
                                       const int wl, const int wreg) {
  const bf16* k0 = kb + (size_t)T0 * TILEELEMS + wl;
  const bf16* k1 = kb + (size_t)T1 * TILEELEMS + wl;
  const bf16* v0 = vb + (size_t)T0 * TILEELEMS + wl;
  const bf16* v1 = vb + (size_t)T1 * TILEELEMS + wl;
  gl_lds16(k0,       slot + wreg);
  gl_lds16(k0 + 512, slot + wreg + 512);
  gl_lds16(k1,       slot + 4096 + wreg);
  gl_lds16(k1 + 512, slot + 4096 + wreg + 512);
  gl_lds16(v0,       slot + 8192 + wreg);
  gl_lds16(v0 + 512, slot + 8192 + wreg + 512);
  gl_lds16(v1,       slot + 12288 + wreg);
  gl_lds16(v1 + 512, slot + 12288 + wreg + 512);
}

// Main loop: LDS double-buffered K/V via global_load_lds, one counted s_waitcnt
// vmcnt(8) per step (waits only for the PREVIOUS step's stages), no barriers, no
// VGPR-destination VMEM in-loop. Each block owns the uniform q-tile pair (31-j, j)
// = exactly 17 p-steps. Grid 512 (2 blocks/CU), lin&7 = XCD = bh&7 for L2 locality.
__global__ __launch_bounds__(256, 1) void attn_kernel(
    const bf16* __restrict__ qp, const bf16* __restrict__ kp,
    const bf16* __restrict__ vp, const float* __restrict__ suf,
    const void* __restrict__ pad, const int* __restrict__ flag,
    bf16* __restrict__ oa)
{
  // 64KB: two 32KB staging slots; epilogue fbuf/obuf/lbuf aliased into slot 0.
  __shared__ __align__(16) bf16 lds[32768];

  const int lin = blockIdx.x;          // 512 blocks
  const int xcd = lin & 7;
  const int t = lin >> 3;              // 0..63
  const int grp = t >> 4;              // 0..3
  const int jq = t & 15;               // q-pair (31-jq, jq): p-steps sum to 17 for all jq
  const int bh = xcd + 8 * grp;
  const int b = bh >> 4, h = bh & 15;

  const int tid = threadIdx.x;
  const int w = tid >> 6, lane = tid & 63, quad = lane >> 4, lc = lane & 15;
  const int bytemode = *flag;

  const int wreg = w * 1024;           // wave-uniform elem offset of this wave's region
  const int wl = wreg + lane * 8;      // per-lane elem offset (16B chunks)
  const int vl = wreg + lane * 4;      // per-lane V-frag elem offset (8B)

  const bf16* kb = kp + (size_t)bh * HEADELEMS;
  const bf16* vb = vp + (size_t)bh * HEADELEMS;

  // ---- precompute pad mask bitmask: pmb[r] bit T = pad[b][T*64 + w*16 + quad*4 + r] ----
  unsigned int pmb[4] = {0u, 0u, 0u, 0u};
  if (bytemode) {
    const unsigned char* pp = (const unsigned char*)pad + b * S_ + w * 16 + quad * 4;
#pragma unroll
    for (int T = 0; T < 32; ++T) {
      const uchar4 u = *(const uchar4*)(pp + T * 64);
      pmb[0] |= (u.x ? 1u : 0u) << T;
      pmb[1] |= (u.y ? 1u : 0u) << T;
      pmb[2] |= (u.z ? 1u : 0u) << T;
      pmb[3] |= (u.w ? 1u : 0u) << T;
    }
  } else {
    const int* pp = (const int*)pad + b * S_ + w * 16 + quad * 4;
#pragma unroll
    for (int T = 0; T < 32; ++T) {
      const int4 u = *(const int4*)(pp + (size_t)T * 64);
      pmb[0] |= (u.x ? 1u : 0u) << T;
      pmb[1] |= (u.y ? 1u : 0u) << T;
      pmb[2] |= (u.z ? 1u : 0u) << T;
      pmb[3] |= (u.w ? 1u : 0u) << T;
    }
  }

#pragma unroll 1
  for (int qsel = 0; qsel < 2; ++qsel) {
    const int myqt = qsel ? jq : 31 - jq;
    const int mynt = myqt + 1;
    const int np = (mynt + 1) >> 1;    // p-steps (2 key-tiles each)

    // ---- prologue: stage Q (8KB, cross-wave shared) into slot1's K_T0 area,
    //      stage p-step 0 into slot 0; drain; barrier; read Q frags; barrier. ----
    const bf16* qb = qp + (size_t)bh * HEADELEMS + (size_t)myqt * TILEELEMS;
    gl_lds16(qb + wl,       lds + 16384 + wreg);
    gl_lds16(qb + wl + 512, lds + 16384 + wreg + 512);
    stage8(kb, vb, lds, 0, 1, wl, wreg);
    asm volatile("s_waitcnt vmcnt(0)" ::: "memory");
    __syncthreads();

    short8 qf[4][2];
#pragma unroll
    for (int qt = 0; qt < 4; ++qt)
#pragma unroll
      for (int hh = 0; hh < 2; ++hh)
        qf[qt][hh] = *(const short8*)(lds + 16384 + qt * 1024 + hh * 512 + lane * 8);
    __syncthreads();   // qf in regs before stage(1) overwrites slot1

    const floatx4 zero4 = {0.f, 0.f, 0.f, 0.f};
    floatx4 oacc[4][4];                            // [dkt][qt]
#pragma unroll
    for (int i = 0; i < 4; ++i)
#pragma unroll
      for (int jj = 0; jj < 4; ++jj) oacc[i][jj] = zero4;
    float lacc[4] = {0.f, 0.f, 0.f, 0.f};

#pragma unroll 1
    for (int p = 0; p < np; ++p) {
      if (p + 1 < np) {
        stage8(kb, vb, lds + (((p + 1) & 1) << 14), 2 * p + 2, 2 * p + 3, wl, wreg);
        asm volatile("s_waitcnt vmcnt(8)" ::: "memory");   // wait for step p's stages only
      } else {
        asm volatile("s_waitcnt vmcnt(0)" ::: "memory");
      }
      __builtin_amdgcn_sched_barrier(0);

      bf16* slot = lds + ((p & 1) << 14);
      const short8 ak00 = *(const short8*)(slot + wl);
      const short8 ak01 = *(const short8*)(slot + wl + 512);
      const short8 ak10 = *(const short8*)(slot + 4096 + wl);
      const short8 ak11 = *(const short8*)(slot + 4096 + wl + 512);
      s4v va0[4], va1[4];
#pragma unroll
      for (int dkt = 0; dkt < 4; ++dkt) {
        va0[dkt] = *(const s4v*)(slot + 8192 + vl + dkt * 256);
        va1[dkt] = *(const s4v*)(slot + 12288 + vl + dkt * 256);
      }

      const int T0 = 2 * p, T1 = 2 * p + 1;
      s4v pf0[4], pf1[4];
      if (p + 1 < np) {
        qk_tile<false>(ak00, ak01, qf, pmb, T0, lacc, pf0, w, quad, lc, false);
        qk_tile<false>(ak10, ak11, qf, pmb, T1, lacc, pf1, w, quad, lc, false);
      } else {  // tail step: contains the diagonal tile (and phantom T1 when mynt odd)
        qk_tile<true>(ak00, ak01, qf, pmb, T0, lacc, pf0, w, quad, lc, T0 == mynt - 1);
        if (T1 < mynt) {
          qk_tile<true>(ak10, ak11, qf, pmb, T1, lacc, pf1, w, quad, lc, true);
        } else {
          const s4v zz = {0, 0, 0, 0};
#pragma unroll
          for (int qt = 0; qt < 4; ++qt) pf1[qt] = zz;   // phantom: covered by suffix sums
        }
      }
      pv_step(va0, va1, pf0, pf1, oacc);
    }

    __syncthreads();   // all waves out of the staging slots before epilogue aliases them

    // ---- epilogue: cross-strip reduction -> LDS out-tile -> full-128B-line stores ----
    // Aliased into slot 0: fbuf bytes [0,17408), obuf [17408,26624), lbuf [26624,27648).
    float* fbuf = (float*)lds;
    bf16* obuf = lds + 8704;
    float* lbuf = (float*)(lds + 13312);

#pragma unroll
    for (int qt = 0; qt < 4; ++qt) {
      float v = lacc[qt];
      v += __shfl_xor(v, 16);
      v += __shfl_xor(v, 32);
      if (quad == 0) lbuf[w * 64 + qt * 16 + lc] = v;
    }
    __syncthreads();
    float ls = lbuf[0 * 64 + w * 16 + lc] + lbuf[1 * 64 + w * 16 + lc]
             + lbuf[2 * 64 + w * 16 + lc] + lbuf[3 * 64 + w * 16 + lc];
    ls += (float)(S_ - mynt * 64);                 // keys past diagonal tile: weight 1 each
    const float linv = 1.f / ls;
    const float* sufp = suf + (size_t)bh * (33 * 64) + mynt * 64;

#pragma unroll
    for (int dktG = 0; dktG < 4; ++dktG) {
#pragma unroll
      for (int qt = 0; qt < 4; ++qt) {
        const floatx4 a = oacc[dktG][qt];
        float* dst = fbuf + (w * 4 + qt) * 272 + lc;
#pragma unroll
        for (int r = 0; r < 4; ++r) dst[(quad * 4 + r) * 17] = a[r];   // stride 17: conflict-free
      }
      __syncthreads();
      // wave w reduces tiles qt == w across the 4 strips
      const float4 sv4 = *(const float4*)(sufp + dktG * 16 + quad * 4);
      float v[4];
#pragma unroll
      for (int r = 0; r < 4; ++r) {
        const int e = (quad * 4 + r) * 17 + lc;
        v[r] = fbuf[(0 * 4 + w) * 272 + e] + fbuf[(1 * 4 + w) * 272 + e]
             + fbuf[(2 * 4 + w) * 272 + e] + fbuf[(3 * 4 + w) * 272 + e];
      }
      v[0] = (v[0] + sv4.x) * linv; v[1] = (v[1] + sv4.y) * linv;
      v[2] = (v[2] + sv4.z) * linv; v[3] = (v[3] + sv4.w) * linv;
      bf16x4 pk = { __float2bfloat16(v[0]), __float2bfloat16(v[1]),
                    __float2bfloat16(v[2]), __float2bfloat16(v[3]) };
      *(bf16x4*)(obuf + (w * 16 + lc) * 72 + dktG * 16 + quad * 4) = pk;
      __syncthreads();
    }

    // store: 2 instructions, each = 8 rows x 128B full lines
    const size_t obase = (size_t)(b * S_ + myqt * 64) * D_ + h * 64;
#pragma unroll
    for (int it = 0; it < 2; ++it) {
      const int idx = it * 256 + tid;
      const int row = idx >> 3, c8 = (idx & 7) * 8;
      const short8 vv = *(const short8*)(obuf + row * 72 + c8);
      *(short8*)(oa + obase + (size_t)row * D_ + c8) = vv;
    }
    __syncthreads();   // epilogue LDS dead before next qsel's staging reuses it
  }
}

extern "C" void kernel_launch(void* const* d_in, const int* in_sizes, int n_in,
                              void* d_out, int out_size, void* d_ws, size_t ws_size,
                              hipStream_t stream) {
  (void)in_sizes; (void)n_in; (void)out_size; (void)ws_size;
  const float* q_in = (const float*)d_in[0];
  const float* k_in = (const float*)d_in[1];
  const float* v_in = (const float*)d_in[2];
  const void*  pmask = d_in[3];
  const float* Wq = (const float*)d_in[4];
  const float* bq = (const float*)d_in[5];
  const float* Wk = (const float*)d_in[6];
  const float* bk = (const float*)d_in[7];
  const float* Wv = (const float*)d_in[8];
  const float* bv = (const float*)d_in[9];
  const float* Wo = (const float*)d_in[10];
  const float* bo = (const float*)d_in[11];

  char* ws = (char*)d_ws;
  bf16* xq  = (bf16*)(ws + 0);
  bf16* xk  = (bf16*)(ws + 8388608);
  bf16* xv  = (bf16*)(ws + 16777216);
  bf16* wqt = (bf16*)(ws + 25165824);
  bf16* wkt = (bf16*)(ws + 27262976);
  bf16* wvt = (bf16*)(ws + 29360128);
  bf16* wot = (bf16*)(ws + 31457280);
  bf16* qpp = (bf16*)(ws + 33554432);
  bf16* kpp = (bf16*)(ws + 41943040);
  bf16* vpp = (bf16*)(ws + 50331648);
  float* suf = (float*)(ws + 25165824);   // overlays wqt (dead after projections)
  int*  flg = (int*)(ws + 58720256);
  bf16* oa  = xq;

  prep_kernel<<<13313, 256, 0, stream>>>(q_in, k_in, v_in, Wq, Wk, Wv, Wo,
                                         xq, xk, xv, wqt, wkt, wvt, wot,
                                         (const unsigned int*)pmask, flg);

  gemm_k<128><<<dim3(32, 8, 3), 256, 0, stream>>>(xq, xk, xv, wqt, wkt, wvt,
                                                  bq, bk, bv, qpp, kpp, vpp, 0, D_, QSCALE);
  suf_kernel<<<32, 256, 0, stream>>>(vpp, suf);

  attn_kernel<<<512, 256, 0, stream>>>(qpp, kpp, vpp, suf, pmask, flg, oa);

  gemm_k<128><<<dim3(32, 8, 1), 256, 0, stream>>>(oa, oa, oa, wot, wot, wot,
                                                  bo, bo, bo, d_out, d_out, d_out, 2, D_, 1.f);
}